// Round 6
// baseline (59.194 us; speedup 1.0000x reference)
//
#include <hip/hip_runtime.h>
#include <math.h>

// MAM "FullyConnected": C[n,m] = max_k(x[n,k]*w[m,k]) + min_k(...) + bias[m]
// plus argmax/argmin (first occurrence). N=1024, M=512, K=512, f32.
// d_out (read back as f32): C | argmax | argmin, each N*M.
//
// Round 6: inline-asm inner loop pinned to 7 VALU per product. k must be a
// VGPR: VOP2 v_cndmask's implicit VCC consumes the scalar-operand slot, so
// SGPR src0 violates the constant-bus restriction (R5 compile failure).

constexpr int NTOT = 1024;
constexpr int MTOT = 512;
constexpr int KTOT = 512;
constexpr int BN = 32;        // output rows per block
constexpr int BM = 32;        // output cols per block
constexpr int BK = 128;       // k-chunk staged in LDS
constexpr int LDSP = BK + 4;  // 132 floats: 16B rows aligned; column b128 reads 2-way aliased (free)

// exactly 7 VALU ops; KV is a VGPR holding k.
// v_cndmask_b32 d, s0, s1, vcc : d = vcc ? s1 : s0
//   vcc = (p <= vmax) -> keep old imax else take k  (first occurrence kept)
#define UPD_ASM(XV, WV, KV, S)                                              \
  {                                                                         \
    float p_;                                                               \
    asm("v_mul_f32 %[p], %[x], %[w]\n\t"                                    \
        "v_cmp_le_f32 vcc, %[p], %[vx]\n\t"                                 \
        "v_cndmask_b32 %[ix], %[k], %[ix], vcc\n\t"                         \
        "v_max_f32 %[vx], %[vx], %[p]\n\t"                                  \
        "v_cmp_ge_f32 vcc, %[p], %[vn]\n\t"                                 \
        "v_cndmask_b32 %[in], %[k], %[in], vcc\n\t"                         \
        "v_min_f32 %[vn], %[vn], %[p]"                                      \
        : [p] "=&v"(p_), [vx] "+v"(vmax##S), [ix] "+v"(imax##S),            \
          [vn] "+v"(vmin##S), [in] "+v"(imin##S)                            \
        : [x] "v"(XV), [w] "v"(WV), [k] "v"(KV)                             \
        : "vcc");                                                           \
  }

__global__ __launch_bounds__(256, 2) void mam_kernel(
    const float* __restrict__ X,   // [NTOT][KTOT]
    const float* __restrict__ W,   // [MTOT][KTOT]
    const float* __restrict__ B,   // [MTOT]
    float* __restrict__ out)
{
  __shared__ float sx[BN][LDSP];
  __shared__ float sw[BM][LDSP];

  const int t  = threadIdx.x;          // 0..255
  const int n0 = blockIdx.y * BN;
  const int m0 = blockIdx.x * BM;

  const int tn = t >> 4;               // 0..15
  const int tm = t & 15;               // 0..15
  const int r0 = tn, r1 = tn + 16;     // 2 output rows
  const int c0 = tm, c1 = tm + 16;     // 2 output cols

  float vmax00 = -INFINITY, vmax01 = -INFINITY, vmax10 = -INFINITY, vmax11 = -INFINITY;
  float vmin00 =  INFINITY, vmin01 =  INFINITY, vmin10 =  INFINITY, vmin11 =  INFINITY;
  int   imax00 = 0, imax01 = 0, imax10 = 0, imax11 = 0;
  int   imin00 = 0, imin01 = 0, imin10 = 0, imin11 = 0;

  #pragma unroll 1
  for (int kc = 0; kc < KTOT; kc += BK) {
    __syncthreads();  // protect LDS from previous iteration's readers
    // stage x[32][128] + w[32][128]: 1024 float4 each, 256 threads -> 4 each
    #pragma unroll
    for (int j = 0; j < 4; ++j) {
      const int id = t + 256 * j;      // 0..1023
      const int r  = id >> 5;          // 0..31
      const int f  = id & 31;          // float4 slot
      *reinterpret_cast<float4*>(&sx[r][f * 4]) =
          *reinterpret_cast<const float4*>(&X[(n0 + r) * KTOT + kc + f * 4]);
      *reinterpret_cast<float4*>(&sw[r][f * 4]) =
          *reinterpret_cast<const float4*>(&W[(m0 + r) * KTOT + kc + f * 4]);
    }
    __syncthreads();

    #pragma unroll 4
    for (int q = 0; q < BK / 4; ++q) {
      const float4 xa = *reinterpret_cast<const float4*>(&sx[r0][q * 4]);
      const float4 xb = *reinterpret_cast<const float4*>(&sx[r1][q * 4]);
      const float4 wa = *reinterpret_cast<const float4*>(&sw[c0][q * 4]);
      const float4 wb = *reinterpret_cast<const float4*>(&sw[c1][q * 4]);
      const int k0 = kc + q * 4;       // compiler puts these in VGPRs (asm wants "v")
      const int k1 = k0 + 1, k2 = k0 + 2, k3 = k0 + 3;

      UPD_ASM(xa.x, wa.x, k0, 00) UPD_ASM(xa.y, wa.y, k1, 00)
      UPD_ASM(xa.z, wa.z, k2, 00) UPD_ASM(xa.w, wa.w, k3, 00)

      UPD_ASM(xa.x, wb.x, k0, 01) UPD_ASM(xa.y, wb.y, k1, 01)
      UPD_ASM(xa.z, wb.z, k2, 01) UPD_ASM(xa.w, wb.w, k3, 01)

      UPD_ASM(xb.x, wa.x, k0, 10) UPD_ASM(xb.y, wa.y, k1, 10)
      UPD_ASM(xb.z, wa.z, k2, 10) UPD_ASM(xb.w, wa.w, k3, 10)

      UPD_ASM(xb.x, wb.x, k0, 11) UPD_ASM(xb.y, wb.y, k1, 11)
      UPD_ASM(xb.z, wb.z, k2, 11) UPD_ASM(xb.w, wb.w, k3, 11)
    }
  }

  // epilogue: C = vmax + vmin + bias; indices as FLOAT values (harness reads f32)
  float* Cout = out;
  float* AM   = out + NTOT * MTOT;
  float* AN   = AM + NTOT * MTOT;

  const float b0 = B[m0 + c0];
  const float b1 = B[m0 + c1];

  const int o00 = (n0 + r0) * MTOT + (m0 + c0);
  const int o01 = (n0 + r0) * MTOT + (m0 + c1);
  const int o10 = (n0 + r1) * MTOT + (m0 + c0);
  const int o11 = (n0 + r1) * MTOT + (m0 + c1);

  Cout[o00] = vmax00 + vmin00 + b0;  AM[o00] = (float)imax00;  AN[o00] = (float)imin00;
  Cout[o01] = vmax01 + vmin01 + b1;  AM[o01] = (float)imax01;  AN[o01] = (float)imin01;
  Cout[o10] = vmax10 + vmin10 + b0;  AM[o10] = (float)imax10;  AN[o10] = (float)imin10;
  Cout[o11] = vmax11 + vmin11 + b1;  AM[o11] = (float)imax11;  AN[o11] = (float)imin11;
}

extern "C" void kernel_launch(void* const* d_in, const int* in_sizes, int n_in,
                              void* d_out, int out_size, void* d_ws, size_t ws_size,
                              hipStream_t stream) {
  const float* X = (const float*)d_in[0];   // [8,128,512] -> [1024][512]
  const float* W = (const float*)d_in[1];   // [512][512]
  const float* B = (const float*)d_in[2];   // [512]
  float* out = (float*)d_out;

  dim3 grid(MTOT / BM, NTOT / BN);          // (16, 32) = 512 blocks
  mam_kernel<<<grid, dim3(256), 0, stream>>>(X, W, B, out);
}

// Round 7
// 58.887 us; speedup vs baseline: 1.0052x; 1.0052x over previous
//
#include <hip/hip_runtime.h>
#include <math.h>

// MAM "FullyConnected": C[n,m] = max_k(x[n,k]*w[m,k]) + min_k(...) + bias[m]
// plus argmax/argmin (first occurrence). N=1024, M=512, K=512, f32.
// d_out (read back as f32): C | argmax | argmin, each N*M.
//
// Round 7: break the VCC serialization found in R6. Four independent cells
// are software-pipelined stage-wise in ONE asm block, each with its own
// SGPR-pair mask (VOP3 v_cmp/v_cndmask) -> dep distance 4 instrs (>=8cy),
// no shared VCC hazards. Exactly 7 VALU ops/product preserved.

constexpr int NTOT = 1024;
constexpr int MTOT = 512;
constexpr int KTOT = 512;
constexpr int BN = 32;        // output rows per block
constexpr int BM = 32;        // output cols per block
constexpr int BK = 128;       // k-chunk staged in LDS
constexpr int LDSP = BK + 4;  // 132 floats: rows 16B-aligned; b128 col reads 2-way aliased (free)

// 4 cells (00,01,10,11) x one k, stage-interleaved, per-cell sgpr-pair masks.
// v_cndmask_b32 d, s0, s1, mask : d = mask ? s1 : s0
//   mask=(p<=vmax) -> keep old imax else take k (first occurrence kept)
#define UPD4(X0, X1, W0, W1, KV)                                            \
  {                                                                         \
    float p00, p01, p10, p11;                                               \
    unsigned long long m00, m01, m10, m11;                                  \
    asm("v_mul_f32 %[p00], %[x0], %[w0]\n\t"                                \
        "v_mul_f32 %[p01], %[x0], %[w1]\n\t"                                \
        "v_mul_f32 %[p10], %[x1], %[w0]\n\t"                                \
        "v_mul_f32 %[p11], %[x1], %[w1]\n\t"                                \
        "v_cmp_le_f32 %[m00], %[p00], %[vx00]\n\t"                          \
        "v_cmp_le_f32 %[m01], %[p01], %[vx01]\n\t"                          \
        "v_cmp_le_f32 %[m10], %[p10], %[vx10]\n\t"                          \
        "v_cmp_le_f32 %[m11], %[p11], %[vx11]\n\t"                          \
        "v_cndmask_b32 %[ix00], %[kv], %[ix00], %[m00]\n\t"                 \
        "v_cndmask_b32 %[ix01], %[kv], %[ix01], %[m01]\n\t"                 \
        "v_cndmask_b32 %[ix10], %[kv], %[ix10], %[m10]\n\t"                 \
        "v_cndmask_b32 %[ix11], %[kv], %[ix11], %[m11]\n\t"                 \
        "v_max_f32 %[vx00], %[vx00], %[p00]\n\t"                            \
        "v_max_f32 %[vx01], %[vx01], %[p01]\n\t"                            \
        "v_max_f32 %[vx10], %[vx10], %[p10]\n\t"                            \
        "v_max_f32 %[vx11], %[vx11], %[p11]\n\t"                            \
        "v_cmp_ge_f32 %[m00], %[p00], %[vn00]\n\t"                          \
        "v_cmp_ge_f32 %[m01], %[p01], %[vn01]\n\t"                          \
        "v_cmp_ge_f32 %[m10], %[p10], %[vn10]\n\t"                          \
        "v_cmp_ge_f32 %[m11], %[p11], %[vn11]\n\t"                          \
        "v_cndmask_b32 %[in00], %[kv], %[in00], %[m00]\n\t"                 \
        "v_cndmask_b32 %[in01], %[kv], %[in01], %[m01]\n\t"                 \
        "v_cndmask_b32 %[in10], %[kv], %[in10], %[m10]\n\t"                 \
        "v_cndmask_b32 %[in11], %[kv], %[in11], %[m11]\n\t"                 \
        "v_min_f32 %[vn00], %[vn00], %[p00]\n\t"                            \
        "v_min_f32 %[vn01], %[vn01], %[p01]\n\t"                            \
        "v_min_f32 %[vn10], %[vn10], %[p10]\n\t"                            \
        "v_min_f32 %[vn11], %[vn11], %[p11]"                                \
        : [p00] "=&v"(p00), [p01] "=&v"(p01), [p10] "=&v"(p10),             \
          [p11] "=&v"(p11),                                                 \
          [m00] "=&s"(m00), [m01] "=&s"(m01), [m10] "=&s"(m10),             \
          [m11] "=&s"(m11),                                                 \
          [vx00] "+v"(vmax00), [vx01] "+v"(vmax01), [vx10] "+v"(vmax10),    \
          [vx11] "+v"(vmax11),                                              \
          [ix00] "+v"(imax00), [ix01] "+v"(imax01), [ix10] "+v"(imax10),    \
          [ix11] "+v"(imax11),                                              \
          [vn00] "+v"(vmin00), [vn01] "+v"(vmin01), [vn10] "+v"(vmin10),    \
          [vn11] "+v"(vmin11),                                              \
          [in00] "+v"(imin00), [in01] "+v"(imin01), [in10] "+v"(imin10),    \
          [in11] "+v"(imin11)                                               \
        : [x0] "v"(X0), [x1] "v"(X1), [w0] "v"(W0), [w1] "v"(W1),           \
          [kv] "v"(KV));                                                    \
  }

__global__ __launch_bounds__(256, 2) void mam_kernel(
    const float* __restrict__ X,   // [NTOT][KTOT]
    const float* __restrict__ W,   // [MTOT][KTOT]
    const float* __restrict__ B,   // [MTOT]
    float* __restrict__ out)
{
  __shared__ float sx[BN][LDSP];
  __shared__ float sw[BM][LDSP];

  const int t  = threadIdx.x;          // 0..255
  const int n0 = blockIdx.y * BN;
  const int m0 = blockIdx.x * BM;

  const int tn = t >> 4;               // 0..15
  const int tm = t & 15;               // 0..15
  const int r0 = tn, r1 = tn + 16;     // 2 output rows
  const int c0 = tm, c1 = tm + 16;     // 2 output cols

  float vmax00 = -INFINITY, vmax01 = -INFINITY, vmax10 = -INFINITY, vmax11 = -INFINITY;
  float vmin00 =  INFINITY, vmin01 =  INFINITY, vmin10 =  INFINITY, vmin11 =  INFINITY;
  int   imax00 = 0, imax01 = 0, imax10 = 0, imax11 = 0;
  int   imin00 = 0, imin01 = 0, imin10 = 0, imin11 = 0;

  #pragma unroll 1
  for (int kc = 0; kc < KTOT; kc += BK) {
    __syncthreads();  // protect LDS from previous iteration's readers
    // stage x[32][128] + w[32][128]: 1024 float4 each, 256 threads -> 4 each
    #pragma unroll
    for (int j = 0; j < 4; ++j) {
      const int id = t + 256 * j;      // 0..1023
      const int r  = id >> 5;          // 0..31
      const int f  = id & 31;          // float4 slot
      *reinterpret_cast<float4*>(&sx[r][f * 4]) =
          *reinterpret_cast<const float4*>(&X[(n0 + r) * KTOT + kc + f * 4]);
      *reinterpret_cast<float4*>(&sw[r][f * 4]) =
          *reinterpret_cast<const float4*>(&W[(m0 + r) * KTOT + kc + f * 4]);
    }
    __syncthreads();

    #pragma unroll 4
    for (int q = 0; q < BK / 4; ++q) {
      const float4 xa = *reinterpret_cast<const float4*>(&sx[r0][q * 4]);
      const float4 xb = *reinterpret_cast<const float4*>(&sx[r1][q * 4]);
      const float4 wa = *reinterpret_cast<const float4*>(&sw[c0][q * 4]);
      const float4 wb = *reinterpret_cast<const float4*>(&sw[c1][q * 4]);
      const int k0 = kc + q * 4;       // in VGPRs for cndmask src0
      const int k1 = k0 + 1, k2 = k0 + 2, k3 = k0 + 3;

      UPD4(xa.x, xb.x, wa.x, wb.x, k0)
      UPD4(xa.y, xb.y, wa.y, wb.y, k1)
      UPD4(xa.z, xb.z, wa.z, wb.z, k2)
      UPD4(xa.w, xb.w, wa.w, wb.w, k3)
    }
  }

  // epilogue: C = vmax + vmin + bias; indices as FLOAT values (harness reads f32)
  float* Cout = out;
  float* AM   = out + NTOT * MTOT;
  float* AN   = AM + NTOT * MTOT;

  const float b0 = B[m0 + c0];
  const float b1 = B[m0 + c1];

  const int o00 = (n0 + r0) * MTOT + (m0 + c0);
  const int o01 = (n0 + r0) * MTOT + (m0 + c1);
  const int o10 = (n0 + r1) * MTOT + (m0 + c0);
  const int o11 = (n0 + r1) * MTOT + (m0 + c1);

  Cout[o00] = vmax00 + vmin00 + b0;  AM[o00] = (float)imax00;  AN[o00] = (float)imin00;
  Cout[o01] = vmax01 + vmin01 + b1;  AM[o01] = (float)imax01;  AN[o01] = (float)imin01;
  Cout[o10] = vmax10 + vmin10 + b0;  AM[o10] = (float)imax10;  AN[o10] = (float)imin10;
  Cout[o11] = vmax11 + vmin11 + b1;  AM[o11] = (float)imax11;  AN[o11] = (float)imin11;
}

extern "C" void kernel_launch(void* const* d_in, const int* in_sizes, int n_in,
                              void* d_out, int out_size, void* d_ws, size_t ws_size,
                              hipStream_t stream) {
  const float* X = (const float*)d_in[0];   // [8,128,512] -> [1024][512]
  const float* W = (const float*)d_in[1];   // [512][512]
  const float* B = (const float*)d_in[2];   // [512]
  float* out = (float*)d_out;

  dim3 grid(MTOT / BM, NTOT / BN);          // (16, 32) = 512 blocks
  mam_kernel<<<grid, dim3(256), 0, stream>>>(X, W, B, out);
}

// Round 8
// 35.097 us; speedup vs baseline: 1.6866x; 1.6778x over previous
//
#include <hip/hip_runtime.h>
#include <math.h>

// MAM "FullyConnected": C[n,m] = max_k(x[n,k]*w[m,k]) + min_k(...) + bias[m]
// plus argmax/argmin (first occurrence). N=1024, M=512, K=512, f32.
// d_out (read back as f32): C | argmax | argmin, each N*M.
//
// Round 8: group-tournament. Evidence (R3-R7): cmp/cndmask/max/min run at
// ~4cy/wave64 (only FMA pipe is 32-wide), so the 7-op/product form is stuck
// at ~28cy/product. New inner loop: per 16-k group per cell, value-only
// max3/min3 trees (no index), one running update per extremum recording the
// GROUP id. Index recovered afterwards from global (L2-resident) by
// rescanning only the winning 16-k window. ~7.5 cy/product.

constexpr int NTOT = 1024;
constexpr int MTOT = 512;
constexpr int KTOT = 512;
constexpr int BN = 32;        // output rows per block
constexpr int BM = 32;        // output cols per block
constexpr int BK = 128;       // k-chunk staged in LDS
constexpr int G  = 16;        // tournament group size
constexpr int LDSP = BK + 4;  // 132: rows 16B-aligned; 2-way b128 aliasing only (free)

__device__ __forceinline__ float max3f(float a, float b, float c) {
  float d; asm("v_max3_f32 %0, %1, %2, %3" : "=v"(d) : "v"(a), "v"(b), "v"(c)); return d;
}
__device__ __forceinline__ float min3f(float a, float b, float c) {
  float d; asm("v_min3_f32 %0, %1, %2, %3" : "=v"(d) : "v"(a), "v"(b), "v"(c)); return d;
}
__device__ __forceinline__ float4 f4mul(float4 a, float4 b) {
  return make_float4(a.x * b.x, a.y * b.y, a.z * b.z, a.w * b.w);
}

// value tree over one 16-k group for one cell + running group update.
// strict > / < : first group attaining the extremum wins (first occurrence).
#define CELL(S, A0, A1, A2, A3, B0, B1, B2, B3)                              \
  {                                                                          \
    const float4 q0 = f4mul(A0, B0), q1 = f4mul(A1, B1);                     \
    const float4 q2 = f4mul(A2, B2), q3 = f4mul(A3, B3);                     \
    const float M = fmaxf(max3f(max3f(q0.x, q0.y, q0.z),                     \
                                max3f(q0.w, q1.x, q1.y),                     \
                                max3f(q1.z, q1.w, q2.x)),                    \
                          max3f(max3f(q2.y, q2.z, q2.w), q3.x,               \
                                max3f(q3.y, q3.z, q3.w)));                   \
    const float m = fminf(min3f(min3f(q0.x, q0.y, q0.z),                     \
                                min3f(q0.w, q1.x, q1.y),                     \
                                min3f(q1.z, q1.w, q2.x)),                    \
                          min3f(min3f(q2.y, q2.z, q2.w), q3.x,               \
                                min3f(q3.y, q3.z, q3.w)));                   \
    const bool u = M > vmax##S;                                              \
    vmax##S = u ? M : vmax##S;  gx##S = u ? gk : gx##S;                      \
    const bool v = m < vmin##S;                                              \
    vmin##S = v ? m : vmin##S;  gn##S = v ? gk : gn##S;                      \
  }

// first k in [base, base+16) with x[k]*w[k] == tgt (descending selects:
// j=0 evaluated last -> smallest j wins -> first occurrence).
__device__ __forceinline__ int find_first_eq(const float* __restrict__ xr,
                                             const float* __restrict__ wr,
                                             float tgt, int base) {
  const float4 a0 = *(const float4*)(xr + 0),  a1 = *(const float4*)(xr + 4);
  const float4 a2 = *(const float4*)(xr + 8),  a3 = *(const float4*)(xr + 12);
  const float4 b0 = *(const float4*)(wr + 0),  b1 = *(const float4*)(wr + 4);
  const float4 b2 = *(const float4*)(wr + 8),  b3 = *(const float4*)(wr + 12);
  int idx = base;
  idx = (a3.w * b3.w == tgt) ? base + 15 : idx;
  idx = (a3.z * b3.z == tgt) ? base + 14 : idx;
  idx = (a3.y * b3.y == tgt) ? base + 13 : idx;
  idx = (a3.x * b3.x == tgt) ? base + 12 : idx;
  idx = (a2.w * b2.w == tgt) ? base + 11 : idx;
  idx = (a2.z * b2.z == tgt) ? base + 10 : idx;
  idx = (a2.y * b2.y == tgt) ? base +  9 : idx;
  idx = (a2.x * b2.x == tgt) ? base +  8 : idx;
  idx = (a1.w * b1.w == tgt) ? base +  7 : idx;
  idx = (a1.z * b1.z == tgt) ? base +  6 : idx;
  idx = (a1.y * b1.y == tgt) ? base +  5 : idx;
  idx = (a1.x * b1.x == tgt) ? base +  4 : idx;
  idx = (a0.w * b0.w == tgt) ? base +  3 : idx;
  idx = (a0.z * b0.z == tgt) ? base +  2 : idx;
  idx = (a0.y * b0.y == tgt) ? base +  1 : idx;
  idx = (a0.x * b0.x == tgt) ? base +  0 : idx;
  return idx;
}

__global__ __launch_bounds__(256, 2) void mam_kernel(
    const float* __restrict__ X,   // [NTOT][KTOT]
    const float* __restrict__ W,   // [MTOT][KTOT]
    const float* __restrict__ B,   // [MTOT]
    float* __restrict__ out)
{
  __shared__ float sx[BN][LDSP];
  __shared__ float sw[BM][LDSP];

  const int t  = threadIdx.x;          // 0..255
  const int n0 = blockIdx.y * BN;
  const int m0 = blockIdx.x * BM;

  const int tn = t >> 4;               // 0..15
  const int tm = t & 15;               // 0..15
  const int r0 = tn, r1 = tn + 16;     // 2 output rows
  const int c0 = tm, c1 = tm + 16;     // 2 output cols

  float vmax00 = -INFINITY, vmax01 = -INFINITY, vmax10 = -INFINITY, vmax11 = -INFINITY;
  float vmin00 =  INFINITY, vmin01 =  INFINITY, vmin10 =  INFINITY, vmin11 =  INFINITY;
  int   gx00 = 0, gx01 = 0, gx10 = 0, gx11 = 0;   // group-start k of running max
  int   gn00 = 0, gn01 = 0, gn10 = 0, gn11 = 0;   // group-start k of running min

  #pragma unroll 1
  for (int kc = 0; kc < KTOT; kc += BK) {
    __syncthreads();  // protect LDS from previous iteration's readers
    // stage x[32][128] + w[32][128]: 1024 float4 each, 256 threads -> 4 each
    #pragma unroll
    for (int j = 0; j < 4; ++j) {
      const int id = t + 256 * j;      // 0..1023
      const int r  = id >> 5;          // 0..31
      const int f  = id & 31;          // float4 slot
      *reinterpret_cast<float4*>(&sx[r][f * 4]) =
          *reinterpret_cast<const float4*>(&X[(n0 + r) * KTOT + kc + f * 4]);
      *reinterpret_cast<float4*>(&sw[r][f * 4]) =
          *reinterpret_cast<const float4*>(&W[(m0 + r) * KTOT + kc + f * 4]);
    }
    __syncthreads();

    #pragma unroll
    for (int g8 = 0; g8 < BK / G; ++g8) {   // 8 groups of 16 k
      const int gk = kc + g8 * G;
      const float4* xap = reinterpret_cast<const float4*>(&sx[r0][g8 * G]);
      const float4* xbp = reinterpret_cast<const float4*>(&sx[r1][g8 * G]);
      const float4* wap = reinterpret_cast<const float4*>(&sw[c0][g8 * G]);
      const float4* wbp = reinterpret_cast<const float4*>(&sw[c1][g8 * G]);
      const float4 xa0 = xap[0], xa1 = xap[1], xa2 = xap[2], xa3 = xap[3];
      const float4 xb0 = xbp[0], xb1 = xbp[1], xb2 = xbp[2], xb3 = xbp[3];
      const float4 wa0 = wap[0], wa1 = wap[1], wa2 = wap[2], wa3 = wap[3];
      const float4 wb0 = wbp[0], wb1 = wbp[1], wb2 = wbp[2], wb3 = wbp[3];

      CELL(00, xa0, xa1, xa2, xa3, wa0, wa1, wa2, wa3)
      CELL(01, xa0, xa1, xa2, xa3, wb0, wb1, wb2, wb3)
      CELL(10, xb0, xb1, xb2, xb3, wa0, wa1, wa2, wa3)
      CELL(11, xb0, xb1, xb2, xb3, wb0, wb1, wb2, wb3)
    }
  }

  // index recovery: rescan only the winning 16-k window per cell (L2 hits)
  const float* Xr0 = &X[(n0 + r0) * KTOT];
  const float* Xr1 = &X[(n0 + r1) * KTOT];
  const float* Wc0 = &W[(m0 + c0) * KTOT];
  const float* Wc1 = &W[(m0 + c1) * KTOT];

  const int imax00 = find_first_eq(Xr0 + gx00, Wc0 + gx00, vmax00, gx00);
  const int imin00 = find_first_eq(Xr0 + gn00, Wc0 + gn00, vmin00, gn00);
  const int imax01 = find_first_eq(Xr0 + gx01, Wc1 + gx01, vmax01, gx01);
  const int imin01 = find_first_eq(Xr0 + gn01, Wc1 + gn01, vmin01, gn01);
  const int imax10 = find_first_eq(Xr1 + gx10, Wc0 + gx10, vmax10, gx10);
  const int imin10 = find_first_eq(Xr1 + gn10, Wc0 + gn10, vmin10, gn10);
  const int imax11 = find_first_eq(Xr1 + gx11, Wc1 + gx11, vmax11, gx11);
  const int imin11 = find_first_eq(Xr1 + gn11, Wc1 + gn11, vmin11, gn11);

  // epilogue: C = vmax + vmin + bias; indices as FLOAT values (harness reads f32)
  float* Cout = out;
  float* AM   = out + NTOT * MTOT;
  float* AN   = AM + NTOT * MTOT;

  const float b0 = B[m0 + c0];
  const float b1 = B[m0 + c1];

  const int o00 = (n0 + r0) * MTOT + (m0 + c0);
  const int o01 = (n0 + r0) * MTOT + (m0 + c1);
  const int o10 = (n0 + r1) * MTOT + (m0 + c0);
  const int o11 = (n0 + r1) * MTOT + (m0 + c1);

  Cout[o00] = vmax00 + vmin00 + b0;  AM[o00] = (float)imax00;  AN[o00] = (float)imin00;
  Cout[o01] = vmax01 + vmin01 + b1;  AM[o01] = (float)imax01;  AN[o01] = (float)imin01;
  Cout[o10] = vmax10 + vmin10 + b0;  AM[o10] = (float)imax10;  AN[o10] = (float)imin10;
  Cout[o11] = vmax11 + vmin11 + b1;  AM[o11] = (float)imax11;  AN[o11] = (float)imin11;
}

extern "C" void kernel_launch(void* const* d_in, const int* in_sizes, int n_in,
                              void* d_out, int out_size, void* d_ws, size_t ws_size,
                              hipStream_t stream) {
  const float* X = (const float*)d_in[0];   // [8,128,512] -> [1024][512]
  const float* W = (const float*)d_in[1];   // [512][512]
  const float* B = (const float*)d_in[2];   // [512]
  float* out = (float*)d_out;

  dim3 grid(MTOT / BM, NTOT / BN);          // (16, 32) = 512 blocks
  mam_kernel<<<grid, dim3(256), 0, stream>>>(X, W, B, out);
}

// Round 9
// 32.613 us; speedup vs baseline: 1.8151x; 1.0762x over previous
//
#include <hip/hip_runtime.h>
#include <math.h>

// MAM "FullyConnected": C[n,m] = max_k(x[n,k]*w[m,k]) + min_k(...) + bias[m]
// plus argmax/argmin (first occurrence). N=1024, M=512, K=512, f32.
// d_out (read back as f32): C | argmax | argmin, each N*M.
//
// Round 9: R8's group-tournament (value-only max3/min3 trees + group-id
// tracking + windowed index recovery) was latency-bound at 2 waves/SIMD
// (VALUBusy 41%). This round k-splits each BK chunk across two wave-groups
// in a 512-thread block -> 4 waves/SIMD with UNCHANGED per-product LDS
// traffic. Products via v_fma_f32(x,w,0) (2-cy FMA pipe; +-0 only diff,
// invisible to compares). Cross-half merge: ties -> min group id.

constexpr int NTOT = 1024;
constexpr int MTOT = 512;
constexpr int KTOT = 512;
constexpr int BN = 32;        // output rows per block
constexpr int BM = 32;        // output cols per block
constexpr int BK = 128;       // k-chunk staged in LDS
constexpr int G  = 16;        // tournament group size
constexpr int LDSP = BK + 4;  // 132: rows 16B-aligned; 2-way b128 aliasing only (free)

__device__ __forceinline__ float max3f(float a, float b, float c) {
  float d; asm("v_max3_f32 %0, %1, %2, %3" : "=v"(d) : "v"(a), "v"(b), "v"(c)); return d;
}
__device__ __forceinline__ float min3f(float a, float b, float c) {
  float d; asm("v_min3_f32 %0, %1, %2, %3" : "=v"(d) : "v"(a), "v"(b), "v"(c)); return d;
}
__device__ __forceinline__ float fmul0(float a, float b) {  // a*b on the FMA pipe
  float d; asm("v_fma_f32 %0, %1, %2, 0" : "=v"(d) : "v"(a), "v"(b)); return d;
}
__device__ __forceinline__ float4 f4mul(float4 a, float4 b) {
  return make_float4(fmul0(a.x, b.x), fmul0(a.y, b.y), fmul0(a.z, b.z), fmul0(a.w, b.w));
}

// value tree over one 16-k group for one cell + running group update.
// strict > / < : first group attaining the extremum wins (first occurrence).
#define CELL(S, A0, A1, A2, A3, B0, B1, B2, B3)                              \
  {                                                                          \
    const float4 q0 = f4mul(A0, B0), q1 = f4mul(A1, B1);                     \
    const float4 q2 = f4mul(A2, B2), q3 = f4mul(A3, B3);                     \
    const float M = fmaxf(max3f(max3f(q0.x, q0.y, q0.z),                     \
                                max3f(q0.w, q1.x, q1.y),                     \
                                max3f(q1.z, q1.w, q2.x)),                    \
                          max3f(max3f(q2.y, q2.z, q2.w), q3.x,               \
                                max3f(q3.y, q3.z, q3.w)));                   \
    const float m = fminf(min3f(min3f(q0.x, q0.y, q0.z),                     \
                                min3f(q0.w, q1.x, q1.y),                     \
                                min3f(q1.z, q1.w, q2.x)),                    \
                          min3f(min3f(q2.y, q2.z, q2.w), q3.x,               \
                                min3f(q3.y, q3.z, q3.w)));                   \
    const bool u = M > vmax##S;                                              \
    vmax##S = u ? M : vmax##S;  gx##S = u ? gk : gx##S;                      \
    const bool v = m < vmin##S;                                              \
    vmin##S = v ? m : vmin##S;  gn##S = v ? gk : gn##S;                      \
  }

// merge the other half's partial for cell S (ties -> smaller group id)
#define MERGE(S, RR, CC)                                                     \
  {                                                                          \
    const int cell = (RR) * 32 + (CC);                                       \
    const float pmx = comb[cell * 4 + 0];                                    \
    const int   pgx = __float_as_int(comb[cell * 4 + 1]);                    \
    const float pmn = comb[cell * 4 + 2];                                    \
    const int   pgn = __float_as_int(comb[cell * 4 + 3]);                    \
    if (pmx > vmax##S) { vmax##S = pmx; gx##S = pgx; }                       \
    else if (pmx == vmax##S && pgx < gx##S) { gx##S = pgx; }                 \
    if (pmn < vmin##S) { vmin##S = pmn; gn##S = pgn; }                       \
    else if (pmn == vmin##S && pgn < gn##S) { gn##S = pgn; }                 \
  }

// first k in [base, base+16) with x[k]*w[k] == tgt (descending selects:
// smallest j evaluated last -> first occurrence wins). +-0 compare-equal,
// so mul here matches the fma-computed target on zeros too.
__device__ __forceinline__ int find_first_eq(const float* __restrict__ xr,
                                             const float* __restrict__ wr,
                                             float tgt, int base) {
  const float4 a0 = *(const float4*)(xr + 0),  a1 = *(const float4*)(xr + 4);
  const float4 a2 = *(const float4*)(xr + 8),  a3 = *(const float4*)(xr + 12);
  const float4 b0 = *(const float4*)(wr + 0),  b1 = *(const float4*)(wr + 4);
  const float4 b2 = *(const float4*)(wr + 8),  b3 = *(const float4*)(wr + 12);
  int idx = base;
  idx = (a3.w * b3.w == tgt) ? base + 15 : idx;
  idx = (a3.z * b3.z == tgt) ? base + 14 : idx;
  idx = (a3.y * b3.y == tgt) ? base + 13 : idx;
  idx = (a3.x * b3.x == tgt) ? base + 12 : idx;
  idx = (a2.w * b2.w == tgt) ? base + 11 : idx;
  idx = (a2.z * b2.z == tgt) ? base + 10 : idx;
  idx = (a2.y * b2.y == tgt) ? base +  9 : idx;
  idx = (a2.x * b2.x == tgt) ? base +  8 : idx;
  idx = (a1.w * b1.w == tgt) ? base +  7 : idx;
  idx = (a1.z * b1.z == tgt) ? base +  6 : idx;
  idx = (a1.y * b1.y == tgt) ? base +  5 : idx;
  idx = (a1.x * b1.x == tgt) ? base +  4 : idx;
  idx = (a0.w * b0.w == tgt) ? base +  3 : idx;
  idx = (a0.z * b0.z == tgt) ? base +  2 : idx;
  idx = (a0.y * b0.y == tgt) ? base +  1 : idx;
  idx = (a0.x * b0.x == tgt) ? base +  0 : idx;
  return idx;
}

__global__ __launch_bounds__(512, 4) void mam_kernel(
    const float* __restrict__ X,   // [NTOT][KTOT]
    const float* __restrict__ W,   // [MTOT][KTOT]
    const float* __restrict__ B,   // [MTOT]
    float* __restrict__ out)
{
  __shared__ float sx[BN][LDSP];
  __shared__ float sw[BM][LDSP];

  const int th   = threadIdx.x;        // 0..511
  const int half = th >> 8;            // 0: kk [0,64), 1: kk [64,128)  (wave-uniform)
  const int t    = th & 255;
  const int n0 = blockIdx.y * BN;
  const int m0 = blockIdx.x * BM;

  const int tn = t >> 4;               // 0..15
  const int tm = t & 15;               // 0..15
  const int r0 = tn, r1 = tn + 16;     // 2 output rows
  const int c0 = tm, c1 = tm + 16;     // 2 output cols
  const int kbase = half * 64;

  float vmax00 = -INFINITY, vmax01 = -INFINITY, vmax10 = -INFINITY, vmax11 = -INFINITY;
  float vmin00 =  INFINITY, vmin01 =  INFINITY, vmin10 =  INFINITY, vmin11 =  INFINITY;
  int   gx00 = 0, gx01 = 0, gx10 = 0, gx11 = 0;   // group-start k of running max
  int   gn00 = 0, gn01 = 0, gn10 = 0, gn11 = 0;   // group-start k of running min

  #pragma unroll 1
  for (int kc = 0; kc < KTOT; kc += BK) {
    __syncthreads();  // protect LDS from previous iteration's readers
    // stage x[32][128] + w[32][128]: 1024 float4 each, 512 threads -> 2+2 each
    #pragma unroll
    for (int j = 0; j < 2; ++j) {
      const int id = th + 512 * j;     // 0..1023
      const int r  = id >> 5;          // 0..31
      const int f  = id & 31;          // float4 slot
      *reinterpret_cast<float4*>(&sx[r][f * 4]) =
          *reinterpret_cast<const float4*>(&X[(n0 + r) * KTOT + kc + f * 4]);
      *reinterpret_cast<float4*>(&sw[r][f * 4]) =
          *reinterpret_cast<const float4*>(&W[(m0 + r) * KTOT + kc + f * 4]);
    }
    __syncthreads();

    #pragma unroll
    for (int g8 = 0; g8 < 4; ++g8) {   // this half's 4 groups of 16 k
      const int off = kbase + g8 * G;
      const int gk  = kc + off;
      const float4* xap = reinterpret_cast<const float4*>(&sx[r0][off]);
      const float4* xbp = reinterpret_cast<const float4*>(&sx[r1][off]);
      const float4* wap = reinterpret_cast<const float4*>(&sw[c0][off]);
      const float4* wbp = reinterpret_cast<const float4*>(&sw[c1][off]);
      const float4 xa0 = xap[0], xa1 = xap[1], xa2 = xap[2], xa3 = xap[3];
      const float4 xb0 = xbp[0], xb1 = xbp[1], xb2 = xbp[2], xb3 = xbp[3];
      const float4 wa0 = wap[0], wa1 = wap[1], wa2 = wap[2], wa3 = wap[3];
      const float4 wb0 = wbp[0], wb1 = wbp[1], wb2 = wbp[2], wb3 = wbp[3];

      CELL(00, xa0, xa1, xa2, xa3, wa0, wa1, wa2, wa3)
      CELL(01, xa0, xa1, xa2, xa3, wb0, wb1, wb2, wb3)
      CELL(10, xb0, xb1, xb2, xb3, wa0, wa1, wa2, wa3)
      CELL(11, xb0, xb1, xb2, xb3, wb0, wb1, wb2, wb3)
    }
  }

  // cross-half combine through LDS (reuse sx storage: 1024 cells * 4 words = 16KB)
  __syncthreads();
  float* comb = &sx[0][0];
  if (half == 1) {
    const int cells[4][2] = {{r0, c0}, {r0, c1}, {r1, c0}, {r1, c1}};
    const float vals[4][2] = {{vmax00, vmin00}, {vmax01, vmin01},
                              {vmax10, vmin10}, {vmax11, vmin11}};
    const int gids[4][2] = {{gx00, gn00}, {gx01, gn01}, {gx10, gn10}, {gx11, gn11}};
    #pragma unroll
    for (int i = 0; i < 4; ++i) {
      const int cell = cells[i][0] * 32 + cells[i][1];
      comb[cell * 4 + 0] = vals[i][0];
      comb[cell * 4 + 1] = __int_as_float(gids[i][0]);
      comb[cell * 4 + 2] = vals[i][1];
      comb[cell * 4 + 3] = __int_as_float(gids[i][1]);
    }
  }
  __syncthreads();

  if (half == 0) {
    MERGE(00, r0, c0)
    MERGE(01, r0, c1)
    MERGE(10, r1, c0)
    MERGE(11, r1, c1)

    // index recovery: rescan only the winning 16-k window per cell (L2 hits)
    const float* Xr0 = &X[(n0 + r0) * KTOT];
    const float* Xr1 = &X[(n0 + r1) * KTOT];
    const float* Wc0 = &W[(m0 + c0) * KTOT];
    const float* Wc1 = &W[(m0 + c1) * KTOT];

    const int imax00 = find_first_eq(Xr0 + gx00, Wc0 + gx00, vmax00, gx00);
    const int imin00 = find_first_eq(Xr0 + gn00, Wc0 + gn00, vmin00, gn00);
    const int imax01 = find_first_eq(Xr0 + gx01, Wc1 + gx01, vmax01, gx01);
    const int imin01 = find_first_eq(Xr0 + gn01, Wc1 + gn01, vmin01, gn01);
    const int imax10 = find_first_eq(Xr1 + gx10, Wc0 + gx10, vmax10, gx10);
    const int imin10 = find_first_eq(Xr1 + gn10, Wc0 + gn10, vmin10, gn10);
    const int imax11 = find_first_eq(Xr1 + gx11, Wc1 + gx11, vmax11, gx11);
    const int imin11 = find_first_eq(Xr1 + gn11, Wc1 + gn11, vmin11, gn11);

    float* Cout = out;
    float* AM   = out + NTOT * MTOT;
    float* AN   = AM + NTOT * MTOT;

    const float b0 = B[m0 + c0];
    const float b1 = B[m0 + c1];

    const int o00 = (n0 + r0) * MTOT + (m0 + c0);
    const int o01 = (n0 + r0) * MTOT + (m0 + c1);
    const int o10 = (n0 + r1) * MTOT + (m0 + c0);
    const int o11 = (n0 + r1) * MTOT + (m0 + c1);

    Cout[o00] = vmax00 + vmin00 + b0;  AM[o00] = (float)imax00;  AN[o00] = (float)imin00;
    Cout[o01] = vmax01 + vmin01 + b1;  AM[o01] = (float)imax01;  AN[o01] = (float)imin01;
    Cout[o10] = vmax10 + vmin10 + b0;  AM[o10] = (float)imax10;  AN[o10] = (float)imin10;
    Cout[o11] = vmax11 + vmin11 + b1;  AM[o11] = (float)imax11;  AN[o11] = (float)imin11;
  }
}

extern "C" void kernel_launch(void* const* d_in, const int* in_sizes, int n_in,
                              void* d_out, int out_size, void* d_ws, size_t ws_size,
                              hipStream_t stream) {
  const float* X = (const float*)d_in[0];   // [8,128,512] -> [1024][512]
  const float* W = (const float*)d_in[1];   // [512][512]
  const float* B = (const float*)d_in[2];   // [512]
  float* out = (float*)d_out;

  dim3 grid(MTOT / BM, NTOT / BN);          // (16, 32) = 512 blocks, 512 thr each
  mam_kernel<<<grid, dim3(512), 0, stream>>>(X, W, B, out);
}